// Round 11
// baseline (242.017 us; speedup 1.0000x reference)
//
#include <hip/hip_runtime.h>
#include <hip/hip_bf16.h>

#define D 128

typedef short short8 __attribute__((ext_vector_type(8)));
typedef float f32x4  __attribute__((ext_vector_type(4)));

__device__ __forceinline__ float lo_bf(unsigned u) { return __uint_as_float(u << 16); }
__device__ __forceinline__ float hi_bf(unsigned u) { return __uint_as_float(u & 0xFFFF0000u); }

// ---------------- Stage 0: wsplit + zero degs ----------------
__global__ void wsplit_zero(const float* __restrict__ W, short* __restrict__ whi,
                            short* __restrict__ wlo, int* __restrict__ degs, int N) {
    int i = blockIdx.x * blockDim.x + threadIdx.x;
    if (i < D * D) {
        float w = W[i];
        unsigned u = __float_as_uint(w);
        float hi = __uint_as_float(u & 0xFFFF0000u);
        float lo = w - hi;
        whi[i] = (short)(u >> 16);
        wlo[i] = (short)(__float_as_uint(lo) >> 16);
    }
    for (int j = i; j < N; j += gridDim.x * blockDim.x) degs[j] = 0;
}

// ---------------- Stage 1: rank = per-dst arrival index (8 edges/thread) ----------------
__global__ void rank_kernel(const int* __restrict__ dst, int* __restrict__ degs,
                            int* __restrict__ rank, int E) {
    int i = blockIdx.x * blockDim.x + threadIdx.x;
    int E8 = E >> 3;
    if (i < E8) {
        int4 a = ((const int4*)dst)[2 * i];
        int4 b = ((const int4*)dst)[2 * i + 1];
        int4 ra, rb;
        ra.x = atomicAdd(&degs[a.x], 1);
        ra.y = atomicAdd(&degs[a.y], 1);
        ra.z = atomicAdd(&degs[a.z], 1);
        ra.w = atomicAdd(&degs[a.w], 1);
        rb.x = atomicAdd(&degs[b.x], 1);
        rb.y = atomicAdd(&degs[b.y], 1);
        rb.z = atomicAdd(&degs[b.z], 1);
        rb.w = atomicAdd(&degs[b.w], 1);
        ((int4*)rank)[2 * i] = ra;
        ((int4*)rank)[2 * i + 1] = rb;
    }
    if (i < (E & 7)) {
        int e = (E & ~7) + i;
        rank[e] = atomicAdd(&degs[dst[e]], 1);
    }
}

// ---------------- Stage 2a: per-block degree sums + norm ----------------
__global__ __launch_bounds__(256) void scan_blocks(
    const int* __restrict__ degs, int* __restrict__ blocksum,
    float* __restrict__ norm, int N)
{
    const int tid = threadIdx.x;
    const int i = blockIdx.x * 256 + tid;
    int d = (i < N) ? degs[i] : 0;
    if (i < N) norm[i] = rsqrtf((float)d + 1.0f);

    int v = d;
    #pragma unroll
    for (int o = 32; o > 0; o >>= 1) v += __shfl_down(v, o, 64);
    __shared__ int ws[4];
    if ((tid & 63) == 0) ws[tid >> 6] = v;
    __syncthreads();
    if (tid == 0) blocksum[blockIdx.x] = ws[0] + ws[1] + ws[2] + ws[3];
}

// ---------------- Stage 2b: final offsets (block sums scanned redundantly per block) ----------------
__global__ __launch_bounds__(256) void scan_final(
    const int* __restrict__ degs, const int* __restrict__ blocksum,
    int* __restrict__ off, int N, int E, int nb)
{
    __shared__ int s[256];
    const int tid = threadIdx.x;
    s[tid] = (tid < nb) ? blocksum[tid] : 0;
    __syncthreads();
    for (int o = 1; o < 256; o <<= 1) {
        int v = (tid >= o) ? s[tid - o] : 0;
        __syncthreads();
        s[tid] += v;
        __syncthreads();
    }
    const int boff = (blockIdx.x == 0) ? 0 : s[blockIdx.x - 1];

    const int i = blockIdx.x * 256 + tid;
    const int lane = tid & 63, w = tid >> 6;
    int d = (i < N) ? degs[i] : 0;

    int v = d;                                   // wave inclusive scan
    #pragma unroll
    for (int o = 1; o < 64; o <<= 1) {
        int t = __shfl_up(v, o, 64);
        if (lane >= o) v += t;
    }
    __shared__ int ws[4];
    if (lane == 63) ws[w] = v;
    __syncthreads();
    int woff = 0;
    #pragma unroll
    for (int k = 0; k < 4; ++k) if (k < w) woff += ws[k];

    int excl = boff + woff + v - d;
    if (i < N) off[i] = excl;
    if (blockIdx.x == 0 && tid == 0) off[N] = E;
}

// ---------------- Stage 3: scatter CSR (no atomics, nontemporal stores, 8/thread) ----------------
__global__ void scatter_kernel(const int* __restrict__ src, const int* __restrict__ dst,
                               const int* __restrict__ efeat, const int* __restrict__ rank,
                               const int* __restrict__ off, unsigned* __restrict__ csr, int E) {
    int i = blockIdx.x * blockDim.x + threadIdx.x;
    int E8 = E >> 3;
    if (i < E8) {
        int4 da = ((const int4*)dst)[2 * i];
        int4 db = ((const int4*)dst)[2 * i + 1];
        int4 sa = ((const int4*)src)[2 * i];
        int4 sb = ((const int4*)src)[2 * i + 1];
        int4 ta = ((const int4*)efeat)[2 * i];
        int4 tb = ((const int4*)efeat)[2 * i + 1];
        int4 ra = ((const int4*)rank)[2 * i];
        int4 rb = ((const int4*)rank)[2 * i + 1];
        int p0 = off[da.x] + ra.x;
        int p1 = off[da.y] + ra.y;
        int p2 = off[da.z] + ra.z;
        int p3 = off[da.w] + ra.w;
        int p4 = off[db.x] + rb.x;
        int p5 = off[db.y] + rb.y;
        int p6 = off[db.z] + rb.z;
        int p7 = off[db.w] + rb.w;
        __builtin_nontemporal_store((unsigned)sa.x | ((unsigned)ta.x << 20), &csr[p0]);
        __builtin_nontemporal_store((unsigned)sa.y | ((unsigned)ta.y << 20), &csr[p1]);
        __builtin_nontemporal_store((unsigned)sa.z | ((unsigned)ta.z << 20), &csr[p2]);
        __builtin_nontemporal_store((unsigned)sa.w | ((unsigned)ta.w << 20), &csr[p3]);
        __builtin_nontemporal_store((unsigned)sb.x | ((unsigned)tb.x << 20), &csr[p4]);
        __builtin_nontemporal_store((unsigned)sb.y | ((unsigned)tb.y << 20), &csr[p5]);
        __builtin_nontemporal_store((unsigned)sb.z | ((unsigned)tb.z << 20), &csr[p6]);
        __builtin_nontemporal_store((unsigned)sb.w | ((unsigned)tb.w << 20), &csr[p7]);
    }
    if (i < (E & 7)) {
        int e = (E & ~7) + i;
        csr[off[dst[e]] + rank[e]] = (unsigned)src[e] | ((unsigned)efeat[e] << 20);
    }
}

// ---------------- Stage 4: h = x @ W^T + b via split-bf16 MFMA (f32-accurate) ----------------
__global__ __launch_bounds__(256) void h_mfma_kernel(
    const float* __restrict__ x, const short* __restrict__ whi, const short* __restrict__ wlo,
    const float* __restrict__ b, __hip_bfloat16* __restrict__ hbf, int N)
{
    const int lane = threadIdx.x & 63;
    const int wave = threadIdx.x >> 6;
    const int m0 = (blockIdx.x * 4 + wave) * 16;
    if (m0 >= N) return;
    const int row  = lane & 15;
    const int quad = lane >> 4;
    int mrow = m0 + row; if (mrow >= N) mrow = N - 1;   // safe dup for ragged tail

    f32x4 acc[8];
    #pragma unroll
    for (int t = 0; t < 8; ++t) acc[t] = (f32x4){0.f, 0.f, 0.f, 0.f};

    #pragma unroll
    for (int kk = 0; kk < 4; ++kk) {
        const int ko = kk * 32 + quad * 8;
        const float4* xp4 = (const float4*)(x + (size_t)mrow * D + ko);
        float4 xa = xp4[0], xb = xp4[1];
        float xv[8] = {xa.x, xa.y, xa.z, xa.w, xb.x, xb.y, xb.z, xb.w};
        short8 ahi, alo;
        #pragma unroll
        for (int j = 0; j < 8; ++j) {
            unsigned u = __float_as_uint(xv[j]);
            float hi = __uint_as_float(u & 0xFFFF0000u);
            float lo = xv[j] - hi;
            ahi[j] = (short)(u >> 16);
            alo[j] = (short)(__float_as_uint(lo) >> 16);
        }
        #pragma unroll
        for (int t = 0; t < 8; ++t) {
            const short8 bhi = *(const short8*)(whi + (size_t)(t * 16 + row) * D + ko);
            const short8 blo = *(const short8*)(wlo + (size_t)(t * 16 + row) * D + ko);
            acc[t] = __builtin_amdgcn_mfma_f32_16x16x32_bf16(ahi, bhi, acc[t], 0, 0, 0);
            acc[t] = __builtin_amdgcn_mfma_f32_16x16x32_bf16(ahi, blo, acc[t], 0, 0, 0);
            acc[t] = __builtin_amdgcn_mfma_f32_16x16x32_bf16(alo, bhi, acc[t], 0, 0, 0);
        }
    }

    #pragma unroll
    for (int t = 0; t < 8; ++t) {
        const int col = t * 16 + row;
        const float bias = b[col];
        #pragma unroll
        for (int r = 0; r < 4; ++r) {
            const int m = m0 + quad * 4 + r;
            if (m < N) hbf[(size_t)m * D + col] = __float2bfloat16(acc[t][r] + bias);
        }
    }
}

// ---------------- Stage 5: gather-aggregate, channel-split 16-lane groups ----------------
// Group g = lane>>4 owns node n = blk*16 + wave*4 + g. Sublane s = lane&15 owns
// channels 8s..8s+7 exclusively (uint4 of the bf16 h-row; 16 lanes = full 256 B row).
// Accumulators are channel-local -> NO cross-lane reduction. 2-edge unroll for MLP.
#define EEP 132
__global__ __launch_bounds__(256) void agg_kernel(
    const int* __restrict__ off, const unsigned* __restrict__ csr,
    const float* __restrict__ norm, const uint4* __restrict__ hbf4,
    const float* __restrict__ ee, const float* __restrict__ res_w,
    float* __restrict__ out, int N)
{
    __shared__ float ees[16 * EEP];
    const int tid = threadIdx.x;
    for (int i = tid; i < 16 * 128; i += 256) {
        int et = i >> 7, c = i & 127;
        ees[et * EEP + c] = ee[i];
    }
    __syncthreads();

    const int wave = tid >> 6;
    const int lane = tid & 63;
    const int g = lane >> 4;     // 4 node-groups per wave
    const int s = lane & 15;     // 16 sublanes: uint4 index -> channels 8s..8s+7
    const int n = blockIdx.x * 16 + wave * 4 + g;
    if (n >= N) return;

    const int beg = off[n], end = off[n + 1];
    const int deg = end - beg;
    const float nd = norm[n];

    float acc[8];
    #pragma unroll
    for (int j = 0; j < 8; ++j) acc[j] = 0.f;

    for (int c = beg; c < end; c += 16) {
        int idx = c + s;
        unsigned se = 0; float en = 0.f;
        if (idx < end) {
            se = csr[idx];
            en = norm[se & 0xFFFFF] * nd;   // lanes beyond cnt keep en=0 (se=0 harmless)
        }
        int cnt = end - c; if (cnt > 16) cnt = 16;
        const int gb = g << 4;
        for (int e = 0; e < cnt; e += 2) {
            unsigned se0 = (unsigned)__shfl((int)se, gb + e);
            float    en0 = __shfl(en, gb + e);
            unsigned se1 = (unsigned)__shfl((int)se, gb + e + 1);
            float    en1 = __shfl(en, gb + e + 1);
            if (e + 1 >= cnt) en1 = 0.f;
            uint4 h0 = hbf4[(size_t)(se0 & 0xFFFFF) * 16 + s];
            uint4 h1 = hbf4[(size_t)(se1 & 0xFFFFF) * 16 + s];
            const float* ep0 = ees + (se0 >> 20) * EEP + 8 * s;
            const float* ep1 = ees + (se1 >> 20) * EEP + 8 * s;
            float4 ea0 = *(const float4*)(ep0);
            float4 eb0 = *(const float4*)(ep0 + 4);
            float4 ea1 = *(const float4*)(ep1);
            float4 eb1 = *(const float4*)(ep1 + 4);
            acc[0] = fmaf(fmaxf(lo_bf(h0.x) + ea0.x, 0.f), en0, acc[0]);
            acc[1] = fmaf(fmaxf(hi_bf(h0.x) + ea0.y, 0.f), en0, acc[1]);
            acc[2] = fmaf(fmaxf(lo_bf(h0.y) + ea0.z, 0.f), en0, acc[2]);
            acc[3] = fmaf(fmaxf(hi_bf(h0.y) + ea0.w, 0.f), en0, acc[3]);
            acc[4] = fmaf(fmaxf(lo_bf(h0.z) + eb0.x, 0.f), en0, acc[4]);
            acc[5] = fmaf(fmaxf(hi_bf(h0.z) + eb0.y, 0.f), en0, acc[5]);
            acc[6] = fmaf(fmaxf(lo_bf(h0.w) + eb0.z, 0.f), en0, acc[6]);
            acc[7] = fmaf(fmaxf(hi_bf(h0.w) + eb0.w, 0.f), en0, acc[7]);
            acc[0] = fmaf(fmaxf(lo_bf(h1.x) + ea1.x, 0.f), en1, acc[0]);
            acc[1] = fmaf(fmaxf(hi_bf(h1.x) + ea1.y, 0.f), en1, acc[1]);
            acc[2] = fmaf(fmaxf(lo_bf(h1.y) + ea1.z, 0.f), en1, acc[2]);
            acc[3] = fmaf(fmaxf(hi_bf(h1.y) + ea1.w, 0.f), en1, acc[3]);
            acc[4] = fmaf(fmaxf(lo_bf(h1.z) + eb1.x, 0.f), en1, acc[4]);
            acc[5] = fmaf(fmaxf(hi_bf(h1.z) + eb1.y, 0.f), en1, acc[5]);
            acc[6] = fmaf(fmaxf(lo_bf(h1.w) + eb1.z, 0.f), en1, acc[6]);
            acc[7] = fmaf(fmaxf(hi_bf(h1.w) + eb1.w, 0.f), en1, acc[7]);
        }
    }

    // residual: relu(h + res_w) / (deg+1); channel-local, no reduction needed
    uint4 hn = hbf4[(size_t)n * 16 + s];
    float invd = 1.0f / (float)(deg + 1);
    const float4* rwp = (const float4*)(res_w + 8 * s);
    float4 r0 = rwp[0], r1 = rwp[1];
    float4 o0, o1;
    o0.x = acc[0] + fmaxf(lo_bf(hn.x) + r0.x, 0.f) * invd;
    o0.y = acc[1] + fmaxf(hi_bf(hn.x) + r0.y, 0.f) * invd;
    o0.z = acc[2] + fmaxf(lo_bf(hn.y) + r0.z, 0.f) * invd;
    o0.w = acc[3] + fmaxf(hi_bf(hn.y) + r0.w, 0.f) * invd;
    o1.x = acc[4] + fmaxf(lo_bf(hn.z) + r1.x, 0.f) * invd;
    o1.y = acc[5] + fmaxf(hi_bf(hn.z) + r1.y, 0.f) * invd;
    o1.z = acc[6] + fmaxf(lo_bf(hn.w) + r1.z, 0.f) * invd;
    o1.w = acc[7] + fmaxf(hi_bf(hn.w) + r1.w, 0.f) * invd;
    float4* op = (float4*)(out + (size_t)n * D + 8 * s);
    op[0] = o0;
    op[1] = o1;
}

extern "C" void kernel_launch(void* const* d_in, const int* in_sizes, int n_in,
                              void* d_out, int out_size, void* d_ws, size_t ws_size,
                              hipStream_t stream) {
    const float* nfeat = (const float*)d_in[0];
    const int* efeat   = (const int*)d_in[1];
    const int* src     = (const int*)d_in[2];
    const int* dst     = (const int*)d_in[3];
    const float* W     = (const float*)d_in[4];
    const float* b     = (const float*)d_in[5];
    const float* ee    = (const float*)d_in[6];
    const float* res_w = (const float*)d_in[7];

    const int N = in_sizes[0] / D;
    const int E = in_sizes[2];
    const int nb = (N + 255) / 256;   // 196 <= 256

    // workspace: degs | off | norm | blocksum | rank | csr | whi | wlo | hbf
    char* p = (char*)d_ws;
    int* degs      = (int*)p;      p += (size_t)N * 4;
    int* off       = (int*)p;      p += (size_t)(N + 1) * 4;
    float* norm    = (float*)p;    p += (size_t)N * 4;
    int* blocksum  = (int*)p;      p += 256 * 4;
    p = (char*)(((uintptr_t)p + 15) & ~(uintptr_t)15);
    int* rank      = (int*)p;      p += (size_t)E * 4;
    unsigned* csr  = (unsigned*)p; p += (size_t)E * 4;
    short* whi     = (short*)p;    p += (size_t)D * D * 2;
    short* wlo     = (short*)p;    p += (size_t)D * D * 2;
    p = (char*)(((uintptr_t)p + 15) & ~(uintptr_t)15);
    __hip_bfloat16* hbf = (__hip_bfloat16*)p;

    wsplit_zero<<<nb, 256, 0, stream>>>(W, whi, wlo, degs, N);

    const int E8 = (E + 7) >> 3;
    rank_kernel<<<(E8 + 255) / 256, 256, 0, stream>>>(dst, degs, rank, E);
    scan_blocks<<<nb, 256, 0, stream>>>(degs, blocksum, norm, N);
    scan_final<<<nb, 256, 0, stream>>>(degs, blocksum, off, N, E, nb);
    scatter_kernel<<<(E8 + 255) / 256, 256, 0, stream>>>(src, dst, efeat, rank, off, csr, E);

    const int mtiles = (N + 15) / 16;
    h_mfma_kernel<<<(mtiles + 3) / 4, 256, 0, stream>>>(nfeat, whi, wlo, b, hbf, N);
    agg_kernel<<<(N + 15) / 16, 256, 0, stream>>>(off, csr, norm, (const uint4*)hbf,
                                                  ee, res_w, (float*)d_out, N);
}